// Round 4
// baseline (204.499 us; speedup 1.0000x reference)
//
#include <hip/hip_runtime.h>

// Problem constants
#define NXC 128
#define NYC 128
#define NZC 4
#define BC  8
#define TC  10

#define TSTRIDE 65536            // NZ*NX*NY
#define BSTRIDE 655360           // TC*TSTRIDE
#define NTOT    5242880          // B*T*NZ*NX*NY

#define TROWS   8                // x-rows per block tile
#define LPITCH  128              // floats per LDS row (no pad: b128 row reads are conflict-free)

__global__ __launch_bounds__(256) void blackoil_kernel(
    const float* __restrict__ pressure,
    const float* __restrict__ perm,
    const float* __restrict__ Q,
    const float* __restrict__ Qw,
    const float* __restrict__ Time_,
    const float* __restrict__ Phi,
    const float* __restrict__ Swini,
    const float* __restrict__ wsat,
    float* __restrict__ out)
{
    __shared__ float ldsK[10 * LPITCH];        // perm t=0 tile (rows x0-1 .. x0+8)
    __shared__ float ldsP[3][10 * LPITCH];     // pressure tile, triple-buffered

    const int tid = threadIdx.x;
    const int blk = blockIdx.x;
    const int xt = blk & 15;                   // x-tile 0..15
    const int z  = (blk >> 4) & 3;
    const int b  = (blk >> 6) & 7;
    const int tc = blk >> 9;                   // 0 or 1 (t-chunk)
    const int t0 = tc * 5;

    const int xr = tid >> 5;                   // 0..7 (row within tile)
    const int y4 = (tid & 31) << 2;            // 0..124

    const int sbase = z * (NXC * NYC) + (xt * TROWS) * NYC;   // (z, x0, 0)
    const int ioff  = xr * NYC + y4;           // interior cell offset from sbase
    const int s     = sbase + ioff;            // own cell within [b,t] slab
    const int loff  = (xr + 1) * LPITCH + y4;  // own cell in LDS (halo row 0)

    // halo staging (tid < 64): hsel 0 -> row x0-1 (clamped), 1 -> row x0+8 (clamped)
    const int hsel = tid >> 5;
    int hrow = hsel ? TROWS : -1;
    if (hsel == 0 && xt == 0)  hrow = 0;
    if (hsel == 1 && xt == 15) hrow = TROWS - 1;
    const int hgoff = hrow * NYC + y4;                    // from sbase
    const int hloff = (hsel ? 9 * LPITCH : 0) + y4;       // LDS dest

    const int pbase = b * BSTRIDE + sbase;

    // ---- prologue: stage perm(t=0) and pressure(t0) tiles ----
    const float4 k0c = *(const float4*)(perm + pbase + ioff);
    float4 pcur      = *(const float4*)(pressure + pbase + t0 * TSTRIDE + ioff);
    float4 kh = {0,0,0,0}, ph = {0,0,0,0};
    if (tid < 64) {
        kh = *(const float4*)(perm + pbase + hgoff);
        ph = *(const float4*)(pressure + pbase + t0 * TSTRIDE + hgoff);
    }
    *(float4*)(ldsK + loff)    = k0c;
    *(float4*)(ldsP[0] + loff) = pcur;
    if (tid < 64) {
        *(float4*)(ldsK + hloff)    = kh;
        *(float4*)(ldsP[0] + hloff) = ph;
    }

    // mobility constants from siniuse = Swini[0,0,0,0,0]
    const float sini = Swini[0];
    const float S0 = (sini - 0.1f) * 1.25f;    // /(1-SWI-SWR)=0.8
    const float cw = S0 * S0;                  // water mobility coeff at t=0
    const float ct = cw + (1.0f - S0) * (1.0f - S0) * (1.0f / 2.75f);

    // prior saturation for first iteration of this t-chunk
    float4 prior;
    if (t0 == 0) { prior.x = prior.y = prior.z = prior.w = sini; }
    else prior = *(const float4*)(wsat + b * BSTRIDE + 4 * TSTRIDE + s);

    __syncthreads();

    // ---- perm0 stencil -> per-thread dpx/dpy registers (t-invariant) ----
    const float4 k0m = *(const float4*)(ldsK + xr * LPITCH + y4);
    const float4 k0p = *(const float4*)(ldsK + (xr + 2) * LPITCH + y4);
    const float kymE = ldsK[(xr + 1) * LPITCH + ((y4 == 0) ? 0 : y4 - 1)];
    const float kypE = ldsK[(xr + 1) * LPITCH + ((y4 == 124) ? 127 : y4 + 4)];

    const float DK = 32000.0f;                 // 500 (perm rescale) * 64 (0.5/h)
    const float dpx[4] = { (k0p.x - k0m.x) * DK, (k0p.y - k0m.y) * DK,
                           (k0p.z - k0m.z) * DK, (k0p.w - k0m.w) * DK };
    const float dpy[4] = { (k0c.y - kymE) * DK, (k0c.z - k0c.x) * DK,
                           (k0c.w - k0c.y) * DK, (kypE - k0c.z) * DK };

    const float scale = 7.8125e-8f;            // dxf * 1e-5 = 1e-5/128

#pragma unroll
    for (int i = 0; i < 5; ++i) {
        const int t  = t0 + i;
        const int tb = b * BSTRIDE + t * TSTRIDE;

        // prefetch next-t pressure tile into registers (consumed by ds_write below)
        float4 nv = {0,0,0,0}, nh = {0,0,0,0};
        if (i < 4) {
            nv = *(const float4*)(pressure + tb + TSTRIDE + s);
            if (tid < 64) nh = *(const float4*)(pressure + tb + TSTRIDE + sbase + hgoff);
        }

        // per-t streams
        const float4 kc  = *(const float4*)(perm  + tb + s);
        const float4 sat = *(const float4*)(wsat  + tb + s);
        const float4 qv  = *(const float4*)(Q     + tb + s);
        const float4 qwv = *(const float4*)(Qw    + tb + s);
        const float4 tv  = *(const float4*)(Time_ + tb + s);
        const float4 phv = *(const float4*)(Phi   + tb + s);

        // pressure stencil: x-neighbors + y-edges from LDS, center from register
        const float* P = ldsP[i % 3];
        const float4 uxm = *(const float4*)(P + xr * LPITCH + y4);
        const float4 uxp = *(const float4*)(P + (xr + 2) * LPITCH + y4);
        const float uymE = P[(xr + 1) * LPITCH + ((y4 == 0) ? 0 : y4 - 1)];
        const float uypE = P[(xr + 1) * LPITCH + ((y4 == 124) ? 127 : y4 + 4)];

        const float ucA [4] = { pcur.x, pcur.y, pcur.z, pcur.w };
        const float uxmA[4] = { uxm.x, uxm.y, uxm.z, uxm.w };
        const float uxpA[4] = { uxp.x, uxp.y, uxp.z, uxp.w };
        const float uymA[4] = { uymE,  pcur.x, pcur.y, pcur.z };
        const float uypA[4] = { pcur.y, pcur.z, pcur.w, uypE };
        const float kcA [4] = { kc.x,  kc.y,  kc.z,  kc.w  };
        const float saA [4] = { sat.x, sat.y, sat.z, sat.w };
        const float prA [4] = { prior.x, prior.y, prior.z, prior.w };
        const float qA  [4] = { qv.x,  qv.y,  qv.z,  qv.w  };
        const float qwA [4] = { qwv.x, qwv.y, qwv.z, qwv.w };
        const float tmA [4] = { tv.x,  tv.y,  tv.z,  tv.w  };
        const float phA [4] = { phv.x, phv.y, phv.z, phv.w };

        float pl[4], sl[4];
#pragma unroll
        for (int j = 0; j < 4; ++j) {
            const float uc   = ucA[j]  * 1000.0f;
            const float uxm2 = uxmA[j] * 1000.0f;
            const float uxp2 = uxpA[j] * 1000.0f;
            const float uym2 = uymA[j] * 1000.0f;
            const float uyp2 = uypA[j] * 1000.0f;

            const float dudx = (uxp2 - uxm2) * 64.0f;
            const float dudy = (uyp2 - uym2) * 64.0f;
            const float lap  = (uxp2 + uxm2 + uyp2 + uym2 - 4.0f * uc) * 16384.0f;

            // dcdx*dudx + dcdy*dudy == ct*g1 ; dadx*dudx + dady*dudy == cw*g1
            const float g1 = dpx[j] * dudx + dpy[j] * dudy;

            const float a   = 500.0f * kcA[j];
            const float dsw = fmaxf(saA[j] - prA[j], 0.001f);
            const float S   = (prA[j] - 0.1f) * 1.25f;
            const float Mw  = S * S;
            const float Mo  = (1.0f - S) * (1.0f - S) * (1.0f / 2.75f);
            const float a1  = (Mw + Mo) * a;
            const float a1w = Mw * a;

            pl[j] = scale * (qA[j] * 5000.0f + ct * g1 + a1 * lap);
            const float flux = cw * g1 + a1w * lap;
            sl[j] = scale * (phA[j] * (dsw / (tmA[j] * 6000.0f)) - (flux + qwA[j] * 5000.0f));
        }

        float4 po = { pl[0], pl[1], pl[2], pl[3] };
        float4 so = { sl[0], sl[1], sl[2], sl[3] };
        *(float4*)(out + tb + s)        = po;
        *(float4*)(out + tb + s + NTOT) = so;

        // publish next-t pressure tile; triple buffer => one barrier per iter is safe
        if (i < 4) {
            float* L = ldsP[(i + 1) % 3];
            *(float4*)(L + loff) = nv;
            if (tid < 64) *(float4*)(L + hloff) = nh;
            pcur = nv;
        }
        prior = sat;
        __syncthreads();
    }
}

extern "C" void kernel_launch(void* const* d_in, const int* in_sizes, int n_in,
                              void* d_out, int out_size, void* d_ws, size_t ws_size,
                              hipStream_t stream) {
    const float* pressure = (const float*)d_in[0];
    const float* perm     = (const float*)d_in[1];
    const float* Q        = (const float*)d_in[2];
    const float* Qw       = (const float*)d_in[3];
    const float* Time_    = (const float*)d_in[4];
    // d_in[5] = Pini (unused by the reference)
    const float* Phi      = (const float*)d_in[6];
    const float* Swini    = (const float*)d_in[7];
    const float* wsat     = (const float*)d_in[8];
    float* out = (float*)d_out;

    // grid: 16 x-tiles * 4 z * 8 b * 2 t-chunks = 1024 blocks (4/CU, all co-resident)
    blackoil_kernel<<<1024, 256, 0, stream>>>(
        pressure, perm, Q, Qw, Time_, Phi, Swini, wsat, out);
}

// Round 6
// 193.656 us; speedup vs baseline: 1.0560x; 1.0560x over previous
//
#include <hip/hip_runtime.h>

// Problem constants
#define NXC 128
#define NYC 128
#define NZC 4
#define BC  8
#define TC  10

#define TSTRIDE 65536            // NZ*NX*NY
#define NTOT    5242880          // B*T*NZ*NX*NY
#define NQUAD   1310720          // NTOT/4
#define HALFQ   655360           // NQUAD/2

// native clang vector (required by __builtin_nontemporal_*)
typedef float vf4 __attribute__((ext_vector_type(4)));

__global__ __launch_bounds__(256) void blackoil_kernel(
    const float* __restrict__ pressure,
    const float* __restrict__ perm,
    const float* __restrict__ Q,
    const float* __restrict__ Qw,
    const float* __restrict__ Time_,
    const float* __restrict__ Phi,
    const float* __restrict__ Swini,
    const float* __restrict__ wsat,
    float* __restrict__ out)
{
    const int gid = blockIdx.x * blockDim.x + threadIdx.x;   // 0..HALFQ-1 exact

    const float sini = Swini[0];

    // per-quad loaded state (2 independent quads => ~26 float4 loads in flight)
    int   base_[2];
    vf4 pc_[2], pxm_[2], pxp_[2];
    float pym_[2], pyp_[2];
    vf4 k0c_[2], k0m_[2], k0p_[2];
    float kym_[2], kyp_[2];
    vf4 kc_[2], sat_[2], pri_[2], qv_[2], qwv_[2], tv_[2], phv_[2];
    int   t_[2];

    // ---------------- load phase: issue everything ----------------
#pragma unroll
    for (int k = 0; k < 2; ++k) {
        const int gq   = gid + k * HALFQ;
        const int base = gq << 2;
        base_[k] = base;

        const int y = base & (NYC - 1);          // multiple of 4
        const int x = (base >> 7) & (NXC - 1);
        const int t = (base >> 16) % TC;
        t_[k] = t;

        const int xm  = (x > 0)        ? -NYC : 0;
        const int xp  = (x < NXC - 1)  ?  NYC : 0;
        const int ymo = (y > 0)        ? -1   : 0;
        const int ypo = (y < NYC - 4)  ?  4   : 3;

        pc_ [k] = *(const vf4*)(pressure + base);
        pxm_[k] = *(const vf4*)(pressure + base + xm);
        pxp_[k] = *(const vf4*)(pressure + base + xp);
        pym_[k] = pressure[base + ymo];
        pyp_[k] = pressure[base + ypo];

        const int i0 = base - t * TSTRIDE;       // perm slice at t=0
        k0c_[k] = *(const vf4*)(perm + i0);
        k0m_[k] = *(const vf4*)(perm + i0 + xm);
        k0p_[k] = *(const vf4*)(perm + i0 + xp);
        kym_[k] = perm[i0 + ymo];
        kyp_[k] = perm[i0 + ypo];

        kc_ [k] = *(const vf4*)(perm + base);
        sat_[k] = *(const vf4*)(wsat + base);
        // unconditional load from a safe address; select sini afterwards
        const int ip = base - ((t > 0) ? TSTRIDE : 0);
        pri_[k] = *(const vf4*)(wsat + ip);

        qv_ [k] = __builtin_nontemporal_load((const vf4*)(Q     + base));
        qwv_[k] = __builtin_nontemporal_load((const vf4*)(Qw    + base));
        tv_ [k] = __builtin_nontemporal_load((const vf4*)(Time_ + base));
        phv_[k] = __builtin_nontemporal_load((const vf4*)(Phi   + base));
    }

    __builtin_amdgcn_sched_barrier(0);   // keep all loads issued before compute

    // mobility constants from siniuse
    const float S0 = (sini - 0.1f) * 1.25f;      // /(1-SWI-SWR)=0.8
    const float cw = S0 * S0;
    const float ct = cw + (1.0f - S0) * (1.0f - S0) * (1.0f / 2.75f);
    const float scale = 7.8125e-8f;              // dxf * 1e-5 = 1e-5/128
    const float DK = 32000.0f;                   // 500 (perm rescale) * 64 (0.5/h)

    // ---------------- compute + store phase ----------------
#pragma unroll
    for (int k = 0; k < 2; ++k) {
        const int base = base_[k];
        vf4 pri = pri_[k];
        if (t_[k] == 0) { pri = (vf4){sini, sini, sini, sini}; }

        const float ucA [4] = { pc_[k].x,  pc_[k].y,  pc_[k].z,  pc_[k].w  };
        const float uxmA[4] = { pxm_[k].x, pxm_[k].y, pxm_[k].z, pxm_[k].w };
        const float uxpA[4] = { pxp_[k].x, pxp_[k].y, pxp_[k].z, pxp_[k].w };
        const float uymA[4] = { pym_[k],   pc_[k].x,  pc_[k].y,  pc_[k].z  };
        const float uypA[4] = { pc_[k].y,  pc_[k].z,  pc_[k].w,  pyp_[k]   };

        const float k0mA[4] = { k0m_[k].x, k0m_[k].y, k0m_[k].z, k0m_[k].w };
        const float k0pA[4] = { k0p_[k].x, k0p_[k].y, k0p_[k].z, k0p_[k].w };
        const float kymA[4] = { kym_[k],   k0c_[k].x, k0c_[k].y, k0c_[k].z };
        const float kypA[4] = { k0c_[k].y, k0c_[k].z, k0c_[k].w, kyp_[k]   };

        const float kcA [4] = { kc_[k].x,  kc_[k].y,  kc_[k].z,  kc_[k].w  };
        const float saA [4] = { sat_[k].x, sat_[k].y, sat_[k].z, sat_[k].w };
        const float prA [4] = { pri.x,     pri.y,     pri.z,     pri.w     };
        const float qA  [4] = { qv_[k].x,  qv_[k].y,  qv_[k].z,  qv_[k].w  };
        const float qwA [4] = { qwv_[k].x, qwv_[k].y, qwv_[k].z, qwv_[k].w };
        const float tmA [4] = { tv_[k].x,  tv_[k].y,  tv_[k].z,  tv_[k].w  };
        const float phA [4] = { phv_[k].x, phv_[k].y, phv_[k].z, phv_[k].w };

        float pl[4], sl[4];
#pragma unroll
        for (int j = 0; j < 4; ++j) {
            const float uc   = ucA[j]  * 1000.0f;
            const float uxm2 = uxmA[j] * 1000.0f;
            const float uxp2 = uxpA[j] * 1000.0f;
            const float uym2 = uymA[j] * 1000.0f;
            const float uyp2 = uypA[j] * 1000.0f;

            const float dudx   = (uxp2 - uxm2) * 64.0f;
            const float dudy   = (uyp2 - uym2) * 64.0f;
            const float dduddx = (uxp2 - 2.0f * uc + uxm2) * 16384.0f;
            const float dduddy = (uyp2 - 2.0f * uc + uym2) * 16384.0f;

            const float dpx = (k0pA[j] - k0mA[j]) * DK;
            const float dpy = (kypA[j] - kymA[j]) * DK;
            const float g1  = dpx * dudx + dpy * dudy;
            const float lap = dduddx + dduddy;

            const float a   = 500.0f * kcA[j];
            const float dsw = fmaxf(saA[j] - prA[j], 0.001f);
            const float S   = (prA[j] - 0.1f) * 1.25f;
            const float Mw  = S * S;
            const float Mo  = (1.0f - S) * (1.0f - S) * (1.0f / 2.75f);
            const float a1  = (Mw + Mo) * a;
            const float a1w = Mw * a;

            pl[j] = scale * (qA[j] * 5000.0f + ct * g1 + a1 * lap);
            const float flux = cw * g1 + a1w * lap;
            sl[j] = scale * (phA[j] * (dsw / (tmA[j] * 6000.0f)) - (flux + qwA[j] * 5000.0f));
        }

        vf4 po = { pl[0], pl[1], pl[2], pl[3] };
        vf4 so = { sl[0], sl[1], sl[2], sl[3] };
        __builtin_nontemporal_store(po, (vf4*)(out + base));
        __builtin_nontemporal_store(so, (vf4*)(out + base + NTOT));
    }
}

extern "C" void kernel_launch(void* const* d_in, const int* in_sizes, int n_in,
                              void* d_out, int out_size, void* d_ws, size_t ws_size,
                              hipStream_t stream) {
    const float* pressure = (const float*)d_in[0];
    const float* perm     = (const float*)d_in[1];
    const float* Q        = (const float*)d_in[2];
    const float* Qw       = (const float*)d_in[3];
    const float* Time_    = (const float*)d_in[4];
    // d_in[5] = Pini (unused by the reference)
    const float* Phi      = (const float*)d_in[6];
    const float* Swini    = (const float*)d_in[7];
    const float* wsat     = (const float*)d_in[8];
    float* out = (float*)d_out;

    const int threads = 256;
    const int blocks  = HALFQ / threads;     // 2560
    blackoil_kernel<<<blocks, threads, 0, stream>>>(
        pressure, perm, Q, Qw, Time_, Phi, Swini, wsat, out);
}